// Round 1
// baseline (421.215 us; speedup 1.0000x reference)
//
#include <hip/hip_runtime.h>
#include <math.h>

#define N_ROWS 200000
#define D 200
#define OUT1 300
#define OUT2 400
#define S1_BLOCKS 512
#define ROWS_PER_ITER 5   // 5 rows x 50 float4 = 250 active threads / 256

// ---------------------------------------------------------------------------
// Stage 1: column-sum of a [N_ROWS, D] f32 matrix (both branches via grid.y).
// partial layout: [2 branches][D cols][S1_BLOCKS] floats (fully written).
// ---------------------------------------------------------------------------
__global__ __launch_bounds__(256)
void colsum_kernel(const float* __restrict__ userH,
                   const float* __restrict__ postH,
                   float* __restrict__ partial)
{
    const int br = blockIdx.y;
    const float* __restrict__ H = (br == 0) ? userH : postH;
    const int t  = threadIdx.x;
    const int q  = t % 50;   // float4 index within the row
    const int sr = t / 50;   // sub-row 0..4 (sr==5 -> idle lanes 250..255)

    float4 acc = make_float4(0.f, 0.f, 0.f, 0.f);
    if (sr < ROWS_PER_ITER) {
        for (int row = blockIdx.x * ROWS_PER_ITER + sr; row < N_ROWS;
             row += S1_BLOCKS * ROWS_PER_ITER) {
            const float4 v =
                *reinterpret_cast<const float4*>(H + (size_t)row * D + q * 4);
            acc.x += v.x; acc.y += v.y; acc.z += v.z; acc.w += v.w;
        }
    }

    __shared__ float part[ROWS_PER_ITER][D];   // 4 KB
    if (sr < ROWS_PER_ITER) {
        part[sr][q * 4 + 0] = acc.x;
        part[sr][q * 4 + 1] = acc.y;
        part[sr][q * 4 + 2] = acc.z;
        part[sr][q * 4 + 3] = acc.w;
    }
    __syncthreads();

    if (t < D) {
        float s = 0.f;
        #pragma unroll
        for (int r = 0; r < ROWS_PER_ITER; ++r) s += part[r][t];
        partial[((size_t)br * D + t) * S1_BLOCKS + blockIdx.x] = s;
    }
}

// ---------------------------------------------------------------------------
// Stage 2: finish reduction -> means -> tiny MLP -> softmax -> output scalar.
// Single block, 512 threads.
// ---------------------------------------------------------------------------
__global__ __launch_bounds__(512)
void mlp_kernel(const float* __restrict__ partial,
                const float* __restrict__ W1u, const float* __restrict__ b1u,
                const float* __restrict__ W2u, const float* __restrict__ b2u,
                const float* __restrict__ W1p, const float* __restrict__ b1p,
                const float* __restrict__ W2p, const float* __restrict__ b2p,
                const float* __restrict__ Wout, const float* __restrict__ bout,
                float* __restrict__ out)
{
    __shared__ float m [2][D];     // column means
    __shared__ float g1[2][OUT1];
    __shared__ float g2[2][OUT2];
    __shared__ float sm[2][OUT2];

    const int t = threadIdx.x;

    // --- finish the column-sum: each of 400 threads owns one (branch,col) ---
    if (t < 2 * D) {
        const float4* p =
            reinterpret_cast<const float4*>(partial + (size_t)t * S1_BLOCKS);
        float4 a = make_float4(0.f, 0.f, 0.f, 0.f);
        for (int k = 0; k < S1_BLOCKS / 4; ++k) {
            const float4 v = p[k];
            a.x += v.x; a.y += v.y; a.z += v.z; a.w += v.w;
        }
        m[t / D][t % D] = (a.x + a.y + a.z + a.w) * (1.0f / (float)N_ROWS);
    }
    __syncthreads();

    // --- g1 = relu(m @ W1 + b1): 2*300 jobs, dot length 200 ---
    for (int p = t; p < 2 * OUT1; p += 512) {
        const int br = p / OUT1;
        const int j  = p % OUT1;
        const float* __restrict__ W1 = br ? W1p : W1u;
        const float* __restrict__ b1 = br ? b1p : b1u;
        float s = b1[j];
        for (int c = 0; c < D; ++c) s += m[br][c] * W1[c * OUT1 + j];
        g1[br][j] = fmaxf(s, 0.f);
    }
    __syncthreads();

    // --- g2 = g1 @ W2 + b2: 2*400 jobs, dot length 300 ---
    for (int p = t; p < 2 * OUT2; p += 512) {
        const int br = p / OUT2;
        const int k  = p % OUT2;
        const float* __restrict__ W2 = br ? W2p : W2u;
        const float* __restrict__ b2 = br ? b2p : b2u;
        float s = b2[k];
        for (int j = 0; j < OUT1; ++j) s += g1[br][j] * W2[j * OUT2 + k];
        g2[br][k] = s;
    }
    __syncthreads();

    // --- softmax per branch: wave 0 -> branch 0, wave 1 -> branch 1 ---
    const int wave = t >> 6;
    const int lane = t & 63;
    if (wave < 2) {
        const int br = wave;
        float mx = -INFINITY;
        for (int k = lane; k < OUT2; k += 64) mx = fmaxf(mx, g2[br][k]);
        #pragma unroll
        for (int off = 32; off > 0; off >>= 1) mx = fmaxf(mx, __shfl_xor(mx, off));
        float sum = 0.f;
        for (int k = lane; k < OUT2; k += 64) {
            const float e = expf(g2[br][k] - mx);
            sm[br][k] = e;
            sum += e;
        }
        #pragma unroll
        for (int off = 32; off > 0; off >>= 1) sum += __shfl_xor(sum, off);
        const float inv = 1.0f / sum;
        for (int k = lane; k < OUT2; k += 64) sm[br][k] *= inv;
    }
    __syncthreads();

    // --- out = sigmoid((sm_u + sm_p) @ W_out + b_out) ---
    if (wave == 0) {
        float s = 0.f;
        for (int k = lane; k < OUT2; k += 64)
            s += (sm[0][k] + sm[1][k]) * Wout[k];
        #pragma unroll
        for (int off = 32; off > 0; off >>= 1) s += __shfl_xor(s, off);
        if (lane == 0)
            out[0] = 1.0f / (1.0f + expf(-(s + bout[0])));
    }
}

// ---------------------------------------------------------------------------
extern "C" void kernel_launch(void* const* d_in, const int* in_sizes, int n_in,
                              void* d_out, int out_size, void* d_ws, size_t ws_size,
                              hipStream_t stream) {
    const float* userH = (const float*)d_in[0];
    const float* postH = (const float*)d_in[1];
    const float* W1u   = (const float*)d_in[2];
    const float* b1u   = (const float*)d_in[3];
    const float* W2u   = (const float*)d_in[4];
    const float* b2u   = (const float*)d_in[5];
    const float* W1p   = (const float*)d_in[6];
    const float* b1p   = (const float*)d_in[7];
    const float* W2p   = (const float*)d_in[8];
    const float* b2p   = (const float*)d_in[9];
    const float* Wout  = (const float*)d_in[10];
    const float* bout  = (const float*)d_in[11];

    float* partial = (float*)d_ws;   // 2*200*512*4 = 819,200 bytes

    dim3 grid1(S1_BLOCKS, 2);
    colsum_kernel<<<grid1, 256, 0, stream>>>(userH, postH, partial);

    mlp_kernel<<<1, 512, 0, stream>>>(partial,
                                      W1u, b1u, W2u, b2u,
                                      W1p, b1p, W2p, b2p,
                                      Wout, bout, (float*)d_out);
}